// Round 8
// baseline (16.776 us; speedup 1.0000x reference)
//
#include <hip/hip_runtime.h>
#include <math.h>

#define BB 384
#define BITS 128
#define NCLS 80
#define NB 24
#define RPB (BB / NB)   // 16 rows per block
#define NT 512

// One dispatch, NB blocks, no memset node.
// Blocks 1..NB-1: pack + count own 16 rows (+ pair loss if a row is valid),
// publish slot, release flag=1 EARLY (~0.4us). Block 0: additionally computes
// ALL of loss2 (hides the cross-XCD flag RT under this work), then polls,
// reduces slots in fixed lane order, writes out, resets flags for next replay.
// First call: flags hold poison != 1; writers overwrite with 1 during the
// call -> spin exits correctly. Deterministic: fixed-order sums everywhere.
__global__ __launch_bounds__(NT) void fused_mb(
    const float* __restrict__ u,
    const int* __restrict__ y,
    float* __restrict__ slots,        // [NB*4]: s1, -, c, -
    unsigned int* __restrict__ flags, // [NB]
    float* __restrict__ out)
{
    const int b = blockIdx.x;
    const int tid = threadIdx.x;
    const int lane = tid & 63;
    const int wave = tid >> 6;        // 0..7

    __shared__ uint4 yw[BB];          // packed labels
    __shared__ float urs[BITS];
    __shared__ float a[BB];
    __shared__ float wred[8], wred2[8];
    __shared__ int   nposs[RPB];

    // --- Phase A: pack all label rows (int4-vectorized, L2-resident) ---
    if (tid < BB) {
        const int4* yi = reinterpret_cast<const int4*>(y + tid * NCLS);
        unsigned int w0 = 0, w1 = 0, w2 = 0;
        #pragma unroll
        for (int q = 0; q < 20; ++q) {
            int4 v = yi[q];
            unsigned int bits = (v.x ? 1u : 0u) | (v.y ? 2u : 0u) |
                                (v.z ? 4u : 0u) | (v.w ? 8u : 0u);
            const int c = q * 4;
            if (c < 32)      w0 |= bits << c;
            else if (c < 64) w1 |= bits << (c - 32);
            else             w2 |= bits << (c - 64);
        }
        yw[tid] = make_uint4(w0, w1, w2, 0u);
    }

    // --- Block 0 only: ALL of loss2 (24 independent float4/thread) ---
    float s2 = 0.f;
    if (b == 0) {
        const float4* u4 = reinterpret_cast<const float4*>(u);
        #pragma unroll
        for (int k = 0; k < (BB * BITS / 4) / NT; ++k) {   // 24
            float4 v = u4[k * NT + tid];
            float d0 = v.x - ((v.x > 0.f) ? 1.f : ((v.x < 0.f) ? -1.f : 0.f));
            float d1 = v.y - ((v.y > 0.f) ? 1.f : ((v.y < 0.f) ? -1.f : 0.f));
            float d2 = v.z - ((v.z > 0.f) ? 1.f : ((v.z < 0.f) ? -1.f : 0.f));
            float d3 = v.w - ((v.w > 0.f) ? 1.f : ((v.w < 0.f) ? -1.f : 0.f));
            s2 += d0 * d0 + d1 * d1 + d2 * d2 + d3 * d3;
        }
    }
    __syncthreads();

    // --- Phase B: positive counts for this block's 16 rows (32 lanes/row) ---
    {
        const int rl = tid >> 5;      // 0..15
        const int sub = tid & 31;
        const uint4 yr = yw[b * RPB + rl];
        int cnt = 0;
        #pragma unroll 4
        for (int i = sub; i < BB; i += 32) {
            uint4 wi = yw[i];
            unsigned int s = (yr.x & wi.x) | (yr.y & wi.y) | (yr.z & wi.z);
            cnt += (s != 0u) ? 1 : 0;
        }
        #pragma unroll
        for (int m = 16; m; m >>= 1) cnt += __shfl_xor(cnt, m, 32);
        if (sub == 0) nposs[rl] = cnt;
    }
    __syncthreads();

    // --- Phase E: general path, fully block-local (skipped: no valid rows) ---
    float s1 = 0.f;
    float cblk = 0.f;                 // uniform across threads
    for (int rl = 0; rl < RPB; ++rl) {
        const int np = nposs[rl];
        const int nn = BB - np;
        if (np <= 0 || nn <= 0) continue;   // block-uniform
        cblk += 1.f;
        const int r = b * RPB + rl;
        const float pc = (float)np * (float)nn;

        if (tid < BITS) urs[tid] = u[r * BITS + tid];
        __syncthreads();
        if (tid < BB) {
            const float* ui = u + tid * BITS;
            float acc = 0.f;
            #pragma unroll 8
            for (int k = 0; k < BITS; k += 4) {
                float4 v = *reinterpret_cast<const float4*>(ui + k);
                acc += urs[k] * v.x + urs[k+1] * v.y + urs[k+2] * v.z + urs[k+3] * v.w;
            }
            a[tid] = acc;
        }
        __syncthreads();

        const uint4 yr = yw[r];
        float part = 0.f;
        for (int i = 0; i < BB; ++i) {
            uint4 wi = yw[i];
            if (((yr.x & wi.x) | (yr.y & wi.y) | (yr.z & wi.z)) == 0u) continue;
            const float ai = a[i] - 0.5f;
            for (int j = tid; j < BB; j += NT) {
                uint4 wj = yw[j];
                if (((yr.x & wj.x) | (yr.y & wj.y) | (yr.z & wj.z)) != 0u) continue;
                float t = ai - a[j];
                t = fminf(fmaxf(t, -100.f), 50.f);
                part += fmaxf(-t, 0.f) + log1pf(expf(-fabsf(t)));  // softplus(-t)
            }
        }
        s1 += part / pc;
        __syncthreads();              // urs/a reused by next valid row
    }

    // --- s1 block reduce only when this block has valid rows (uniform) ---
    float S1 = 0.f;
    if (cblk > 0.f) {
        float v1 = s1;
        #pragma unroll
        for (int o = 32; o; o >>= 1) v1 += __shfl_down(v1, o, 64);
        if (lane == 0) wred[wave] = v1;
        __syncthreads();
        if (tid == 0) {
            #pragma unroll
            for (int w = 0; w < 8; ++w) S1 += wred[w];
        }
    }

    // --- publish slot + early flag (b>0) ---
    if (tid == 0) {
        __hip_atomic_store(&slots[b * 4 + 0], S1, __ATOMIC_RELAXED, __HIP_MEMORY_SCOPE_AGENT);
        __hip_atomic_store(&slots[b * 4 + 2], cblk, __ATOMIC_RELAXED, __HIP_MEMORY_SCOPE_AGENT);
        if (b != 0)
            __hip_atomic_store(&flags[b], 1u, __ATOMIC_RELEASE, __HIP_MEMORY_SCOPE_AGENT);
    }

    // --- block 0: reduce own s2, poll flags, final fixed-order reduce ---
    if (b == 0) {
        float v2 = s2;
        #pragma unroll
        for (int o = 32; o; o >>= 1) v2 += __shfl_down(v2, o, 64);
        if (lane == 0) wred2[wave] = v2;

        if (tid > 0 && tid < NB) {
            while (__hip_atomic_load(&flags[tid], __ATOMIC_ACQUIRE,
                                     __HIP_MEMORY_SCOPE_AGENT) != 1u) {}
        }
        __syncthreads();

        if (tid < 64) {
            float r1 = 0.f, rc = 0.f;
            if (tid < NB) {
                r1 = __hip_atomic_load(&slots[tid * 4 + 0], __ATOMIC_RELAXED, __HIP_MEMORY_SCOPE_AGENT);
                rc = __hip_atomic_load(&slots[tid * 4 + 2], __ATOMIC_RELAXED, __HIP_MEMORY_SCOPE_AGENT);
            }
            #pragma unroll
            for (int o = 32; o; o >>= 1) {
                r1 += __shfl_down(r1, o, 64);
                rc += __shfl_down(rc, o, 64);
            }
            if (tid == 0) {
                float S2 = 0.f;
                #pragma unroll
                for (int w = 0; w < 8; ++w) S2 += wred2[w];
                const float count = rc;
                const float loss1 = (count > 0.f) ? (r1 / fmaxf(count, 1.f)) : 0.f;
                const float loss2 = 0.1f * S2 / (float)(BB * BITS);
                out[0] = loss1 + loss2;
            }
            if (tid > 0 && tid < NB)  // reset for next replay (stream-serialized)
                __hip_atomic_store(&flags[tid], 0u, __ATOMIC_RELAXED, __HIP_MEMORY_SCOPE_AGENT);
        }
    }
}

extern "C" void kernel_launch(void* const* d_in, const int* in_sizes, int n_in,
                              void* d_out, int out_size, void* d_ws, size_t ws_size,
                              hipStream_t stream) {
    const float* u = (const float*)d_in[0];
    const int*   y = (const int*)d_in[1];
    float* out = (float*)d_out;

    float* slots = (float*)d_ws;                           // NB*4 floats
    unsigned int* flags = (unsigned int*)(slots + NB * 4); // NB words

    fused_mb<<<NB, NT, 0, stream>>>(u, y, slots, flags, out);
}

// Round 9
// 12.254 us; speedup vs baseline: 1.3690x; 1.3690x over previous
//
#include <hip/hip_runtime.h>
#include <math.h>

#define BB 384
#define BITS 128
#define NCLS 80
#define NB 24
#define RPB (BB / NB)   // 16 rows per block
#define NT 512

// One dispatch, NB balanced blocks, no memset node.
// Every block: loss2 slice (1 float4/thread, load issued first), pack all
// 384 label masks, count positives for its 16 rows, (general path: pair loss
// for any valid row), publish slot, release flag. Block 0 additionally polls
// the 23 flags, reduces slots in fixed lane order, writes out, resets flags
// for the next replay (stream-serialized => race-free).
// First call: flags hold poison != 1; writers store 1 during the call.
// Deterministic: fixed-order sums everywhere, no float atomics.
__global__ __launch_bounds__(NT) void fused_mb(
    const float* __restrict__ u,
    const int* __restrict__ y,
    float* __restrict__ slots,        // [NB*4]: s1, s2, c, pad
    unsigned int* __restrict__ flags, // [NB]
    float* __restrict__ out)
{
    const int b = blockIdx.x;
    const int tid = threadIdx.x;
    const int lane = tid & 63;
    const int wave = tid >> 6;        // 0..7

    __shared__ uint4 yw[BB];          // packed labels
    __shared__ float urs[BITS];
    __shared__ float a[BB];
    __shared__ float wred[8], wred2[8];
    __shared__ int   nposs[RPB];

    // --- loss2 slice: issue the global load FIRST (latency hides under pack)
    const float4* u4 = reinterpret_cast<const float4*>(u);
    float4 lv = u4[b * NT + tid];     // 24*512 = 12288 float4 = all of u

    // --- Phase A: pack all label rows (int4-vectorized, L2-resident) ---
    if (tid < BB) {
        const int4* yi = reinterpret_cast<const int4*>(y + tid * NCLS);
        unsigned int w0 = 0, w1 = 0, w2 = 0;
        #pragma unroll
        for (int q = 0; q < 20; ++q) {
            int4 v = yi[q];
            unsigned int bits = (v.x ? 1u : 0u) | (v.y ? 2u : 0u) |
                                (v.z ? 4u : 0u) | (v.w ? 8u : 0u);
            const int c = q * 4;
            if (c < 32)      w0 |= bits << c;
            else if (c < 64) w1 |= bits << (c - 32);
            else             w2 |= bits << (c - 64);
        }
        yw[tid] = make_uint4(w0, w1, w2, 0u);
    }

    // consume loss2 load while pack stores drain
    float s2;
    {
        float d0 = lv.x - ((lv.x > 0.f) ? 1.f : ((lv.x < 0.f) ? -1.f : 0.f));
        float d1 = lv.y - ((lv.y > 0.f) ? 1.f : ((lv.y < 0.f) ? -1.f : 0.f));
        float d2 = lv.z - ((lv.z > 0.f) ? 1.f : ((lv.z < 0.f) ? -1.f : 0.f));
        float d3 = lv.w - ((lv.w > 0.f) ? 1.f : ((lv.w < 0.f) ? -1.f : 0.f));
        s2 = d0 * d0 + d1 * d1 + d2 * d2 + d3 * d3;
    }
    __syncthreads();

    // --- Phase B: positive counts for this block's 16 rows (32 lanes/row) ---
    {
        const int rl = tid >> 5;      // 0..15
        const int sub = tid & 31;
        const uint4 yr = yw[b * RPB + rl];
        int cnt = 0;
        #pragma unroll 4
        for (int i = sub; i < BB; i += 32) {
            uint4 wi = yw[i];
            unsigned int s = (yr.x & wi.x) | (yr.y & wi.y) | (yr.z & wi.z);
            cnt += (s != 0u) ? 1 : 0;
        }
        #pragma unroll
        for (int m = 16; m; m >>= 1) cnt += __shfl_xor(cnt, m, 32);
        if (sub == 0) nposs[rl] = cnt;
    }
    __syncthreads();

    // --- Phase E: general path, fully block-local (skipped: no valid rows) ---
    float s1 = 0.f;
    float cblk = 0.f;                 // uniform across threads
    for (int rl = 0; rl < RPB; ++rl) {
        const int np = nposs[rl];
        const int nn = BB - np;
        if (np <= 0 || nn <= 0) continue;   // block-uniform
        cblk += 1.f;
        const int r = b * RPB + rl;
        const float pc = (float)np * (float)nn;

        if (tid < BITS) urs[tid] = u[r * BITS + tid];
        __syncthreads();
        if (tid < BB) {
            const float* ui = u + tid * BITS;
            float acc = 0.f;
            #pragma unroll 8
            for (int k = 0; k < BITS; k += 4) {
                float4 v = *reinterpret_cast<const float4*>(ui + k);
                acc += urs[k] * v.x + urs[k+1] * v.y + urs[k+2] * v.z + urs[k+3] * v.w;
            }
            a[tid] = acc;
        }
        __syncthreads();

        const uint4 yr = yw[r];
        float part = 0.f;
        for (int i = 0; i < BB; ++i) {
            uint4 wi = yw[i];
            if (((yr.x & wi.x) | (yr.y & wi.y) | (yr.z & wi.z)) == 0u) continue;
            const float ai = a[i] - 0.5f;
            for (int j = tid; j < BB; j += NT) {
                uint4 wj = yw[j];
                if (((yr.x & wj.x) | (yr.y & wj.y) | (yr.z & wj.z)) != 0u) continue;
                float t = ai - a[j];
                t = fminf(fmaxf(t, -100.f), 50.f);
                part += fmaxf(-t, 0.f) + log1pf(expf(-fabsf(t)));  // softplus(-t)
            }
        }
        s1 += part / pc;
        __syncthreads();              // urs/a reused by next valid row
    }

    // --- block reduce: s2 always; s1 only if this block had valid rows ---
    float v2 = s2;
    #pragma unroll
    for (int o = 32; o; o >>= 1) v2 += __shfl_down(v2, o, 64);
    if (lane == 0) wred2[wave] = v2;
    if (cblk > 0.f) {                 // uniform branch
        float v1 = s1;
        #pragma unroll
        for (int o = 32; o; o >>= 1) v1 += __shfl_down(v1, o, 64);
        if (lane == 0) wred[wave] = v1;
    } else if (lane == 0) {
        wred[wave] = 0.f;
    }
    __syncthreads();

    // --- publish slot + flag (b>0) ---
    if (tid == 0) {
        float S1 = 0.f, S2 = 0.f;
        #pragma unroll
        for (int w = 0; w < 8; ++w) { S1 += wred[w]; S2 += wred2[w]; }
        __hip_atomic_store(&slots[b * 4 + 0], S1, __ATOMIC_RELAXED, __HIP_MEMORY_SCOPE_AGENT);
        __hip_atomic_store(&slots[b * 4 + 1], S2, __ATOMIC_RELAXED, __HIP_MEMORY_SCOPE_AGENT);
        __hip_atomic_store(&slots[b * 4 + 2], cblk, __ATOMIC_RELAXED, __HIP_MEMORY_SCOPE_AGENT);
        if (b != 0)
            __hip_atomic_store(&flags[b], 1u, __ATOMIC_RELEASE, __HIP_MEMORY_SCOPE_AGENT);
    }

    // --- block 0: poll flags, final fixed-order reduce, reset flags ---
    if (b == 0) {
        if (tid > 0 && tid < NB) {
            while (__hip_atomic_load(&flags[tid], __ATOMIC_ACQUIRE,
                                     __HIP_MEMORY_SCOPE_AGENT) != 1u) {}
        }
        __syncthreads();
        if (tid < 32) {               // NB=24 fits in half a wave
            float r1 = 0.f, r2 = 0.f, rc = 0.f;
            if (tid < NB) {
                r1 = __hip_atomic_load(&slots[tid * 4 + 0], __ATOMIC_RELAXED, __HIP_MEMORY_SCOPE_AGENT);
                r2 = __hip_atomic_load(&slots[tid * 4 + 1], __ATOMIC_RELAXED, __HIP_MEMORY_SCOPE_AGENT);
                rc = __hip_atomic_load(&slots[tid * 4 + 2], __ATOMIC_RELAXED, __HIP_MEMORY_SCOPE_AGENT);
            }
            #pragma unroll
            for (int o = 16; o; o >>= 1) {
                r1 += __shfl_down(r1, o, 32);
                r2 += __shfl_down(r2, o, 32);
                rc += __shfl_down(rc, o, 32);
            }
            if (tid == 0) {
                const float count = rc;
                const float loss1 = (count > 0.f) ? (r1 / fmaxf(count, 1.f)) : 0.f;
                const float loss2 = 0.1f * r2 / (float)(BB * BITS);
                out[0] = loss1 + loss2;
            }
            if (tid > 0 && tid < NB)  // reset for next replay (stream-serialized)
                __hip_atomic_store(&flags[tid], 0u, __ATOMIC_RELAXED, __HIP_MEMORY_SCOPE_AGENT);
        }
    }
}

extern "C" void kernel_launch(void* const* d_in, const int* in_sizes, int n_in,
                              void* d_out, int out_size, void* d_ws, size_t ws_size,
                              hipStream_t stream) {
    const float* u = (const float*)d_in[0];
    const int*   y = (const int*)d_in[1];
    float* out = (float*)d_out;

    float* slots = (float*)d_ws;                           // NB*4 floats
    unsigned int* flags = (unsigned int*)(slots + NB * 4); // NB words

    fused_mb<<<NB, NT, 0, stream>>>(u, y, slots, flags, out);
}